// Round 5
// baseline (1239.464 us; speedup 1.0000x reference)
//
#include <hip/hip_runtime.h>

#define N_TOT 10000
#define CLS_P 1000
#define NC 10
#define D 1024

#define TM 128            // block tile (i and j)
#define LDT 40            // LDS row stride in halves (32+8): 80B = 5x16B aligned, 2-way-free banks
#define DELTA 2.5e-5f
#define INV_SCALE2 4.8828125e-4f   // 2 / 4096  (Xh stores 64*x; acc = 4096*dot)
#define ESC_CAP (1 << 22)
#define KCHUNKS (D / 32)

typedef _Float16 f16x8 __attribute__((ext_vector_type(8)));
typedef float f32x4 __attribute__((ext_vector_type(4)));

// ---------------- zero output + escalation counter ----------------
__global__ void zero_kernel(int* __restrict__ out, int n, int* __restrict__ esc_cnt) {
    int i = blockIdx.x * blockDim.x + threadIdx.x;
    if (i < n) out[i] = 0;
    if (i == 0) *esc_cnt = 0;
}

// ---------------- gather + fp16(64x) + fp64 norms ----------------
__global__ void prep_kernel(const float* __restrict__ feats, const int* __restrict__ ids,
                            unsigned short* __restrict__ Xh,
                            double* __restrict__ sqd, float* __restrict__ sqf) {
    int row = blockIdx.x;
    int id = ids[row];
    const float4* rp = (const float4*)(feats + (size_t)id * D);
    float4 v = rp[threadIdx.x];  // 256 threads * 4 = 1024
    float f[4] = {v.x, v.y, v.z, v.w};
    ushort4 hv;
    unsigned short* hp = &hv.x;
    double s = 0.0;
    #pragma unroll
    for (int e = 0; e < 4; e++) {
        s += (double)f[e] * f[e];
        union { _Float16 h; unsigned short u; } cv;
        cv.h = (_Float16)(f[e] * 64.0f);   // RNE; x64 avoids fp16 denormals
        hp[e] = cv.u;
    }
    *(ushort4*)(Xh + (size_t)row * D + threadIdx.x * 4) = hv;

    #pragma unroll
    for (int off = 32; off > 0; off >>= 1)
        s += __shfl_down(s, off, 64);
    __shared__ double wsum[4];
    int lane = threadIdx.x & 63, wv = threadIdx.x >> 6;
    if (lane == 0) wsum[wv] = s;
    __syncthreads();
    if (threadIdx.x == 0) {
        double t = wsum[0] + wsum[1] + wsum[2] + wsum[3];
        sqd[row] = t;
        sqf[row] = (float)t;
    }
}

// ---------------- fp16 MFMA pairwise count (upper-triangle, reg-prefetch dbuf) ----------------
__launch_bounds__(256, 3)
__global__ void count_kernel(const unsigned short* __restrict__ Xh,
                             const float* __restrict__ sqf,
                             int* __restrict__ counts,
                             int* __restrict__ esc_cnt, int2* __restrict__ esc_list) {
    const int ib = blockIdx.x * TM, jb = blockIdx.y * TM;
    if (jb < ib) return;  // symmetric: only upper triangle of tiles

    // skip tiles that are entirely same-class
    {
        int ci0 = ib / CLS_P, ci1 = (ib + TM - 1) / CLS_P;
        int cj0 = jb / CLS_P, cj1 = (jb + TM - 1) / CLS_P;
        if (ci0 == ci1 && cj0 == cj1 && ci0 == cj0) return;
    }

    __shared__ unsigned short Sa[2 * TM * LDT];   // 20 KB
    __shared__ unsigned short Sb[2 * TM * LDT];   // 20 KB
    __shared__ int cred_i[TM], cred_j[TM];

    const int tid = threadIdx.x;
    const int lane = tid & 63, w = tid >> 6;
    const int wi = (w & 1) * 64, wj = (w >> 1) * 64;
    const int quad = lane >> 4, col = lane & 15;
    const int kq8 = quad * 8;

    // staging mapping: lanes (2k,2k+1) cover row k's 64B chunk
    const int s_row = tid >> 1;           // 0..127
    const int s_kh = (tid & 1) * 16;      // half-offset 0 or 16

    int ga = ib + s_row; if (ga > N_TOT - 1) ga = N_TOT - 1;
    int gb = jb + s_row; if (gb > N_TOT - 1) gb = N_TOT - 1;
    const unsigned short* gpa = Xh + (size_t)ga * D + s_kh;
    const unsigned short* gpb = Xh + (size_t)gb * D + s_kh;

    uint4 pfA[2][2], pfB[2][2];

#define GLOAD(PH, KC_)                                              \
    {                                                               \
        const unsigned short* pa = gpa + (KC_) * 32;                \
        const unsigned short* pb = gpb + (KC_) * 32;                \
        pfA[PH][0] = *(const uint4*)(pa);                           \
        pfA[PH][1] = *(const uint4*)(pa + 8);                       \
        pfB[PH][0] = *(const uint4*)(pb);                           \
        pfB[PH][1] = *(const uint4*)(pb + 8);                       \
    }

#define SWRITE(PH, BUF_)                                            \
    {                                                               \
        unsigned short* da = Sa + (BUF_) * (TM * LDT) + s_row * LDT + s_kh; \
        unsigned short* db = Sb + (BUF_) * (TM * LDT) + s_row * LDT + s_kh; \
        *(uint4*)(da) = pfA[PH][0];                                 \
        *(uint4*)(da + 8) = pfA[PH][1];                             \
        *(uint4*)(db) = pfB[PH][0];                                 \
        *(uint4*)(db + 8) = pfB[PH][1];                             \
    }

    f32x4 acc[4][4];
    #pragma unroll
    for (int it = 0; it < 4; it++)
        #pragma unroll
        for (int jt = 0; jt < 4; jt++)
            acc[it][jt] = (f32x4){0.f, 0.f, 0.f, 0.f};

    // prologue: buf0 <- kc0; pf[1] <- kc1
    GLOAD(0, 0);
    SWRITE(0, 0);
    GLOAD(1, 1);
    __syncthreads();

    for (int kc = 0; kc < KCHUNKS; kc++) {
        const int buf = kc & 1;
        if (kc + 2 < KCHUNKS) GLOAD(kc & 1, kc + 2);

        f16x8 ah[4], bh[4];
        #pragma unroll
        for (int t = 0; t < 4; t++) {
            ah[t] = *(const f16x8*)(Sa + buf * (TM * LDT) + (wi + t * 16 + col) * LDT + kq8);
            bh[t] = *(const f16x8*)(Sb + buf * (TM * LDT) + (wj + t * 16 + col) * LDT + kq8);
        }
        if (kc + 1 < KCHUNKS) SWRITE((kc + 1) & 1, buf ^ 1);
        __syncthreads();   // lgkm-only drain: no vmem pending at barrier

        #pragma unroll
        for (int it = 0; it < 4; it++)
            #pragma unroll
            for (int jt = 0; jt < 4; jt++)
                acc[it][jt] = __builtin_amdgcn_mfma_f32_16x16x32_f16(ah[it], bh[jt], acc[it][jt], 0, 0, 0);
    }

    // ---------------- epilogue: threshold + ballot-aggregated escalate + symmetric reduce ----------------
    if (tid < TM) { cred_i[tid] = 0; cred_j[tid] = 0; }
    __syncthreads();

    const float thr_lo = 0.25f - DELTA;
    const float thr_hi = 0.25f + DELTA;
    const bool diag = (ib == jb);

    float sqj[4];
    int clsj[4], jv[4], jidx[4];
    #pragma unroll
    for (int jt = 0; jt < 4; jt++) {
        int j = jb + wj + jt * 16 + col;
        jidx[jt] = j;
        jv[jt] = (j < N_TOT);
        sqj[jt] = jv[jt] ? sqf[j] : 0.f;
        clsj[jt] = j / CLS_P;
    }

    int cj[4] = {0, 0, 0, 0};

    #pragma unroll
    for (int it = 0; it < 4; it++) {
        #pragma unroll
        for (int r = 0; r < 4; r++) {
            int irow = wi + it * 16 + quad * 4 + r;
            int i = ib + irow;
            bool iv = (i < N_TOT);
            float sqi = iv ? sqf[i] : 0.f;
            int clsi = i / CLS_P;
            int ci = 0;
            #pragma unroll
            for (int jt = 0; jt < 4; jt++) {
                int j = jidx[jt];
                bool ok = iv && jv[jt] && (clsj[jt] != clsi) && (!diag || j > i);
                float d2 = sqi + sqj[jt] - acc[it][jt][r] * INV_SCALE2;
                bool in = ok && (d2 < thr_lo);
                bool esc = ok && !in && (d2 < thr_hi);
                ci += in ? 1 : 0;
                cj[jt] += in ? 1 : 0;
                unsigned long long m = __ballot(esc);
                if (m) {
                    int leader = __ffsll(m) - 1;
                    int cntw = __popcll(m);
                    int pre = __popcll(m & ((1ull << lane) - 1));
                    int base = 0;
                    if (lane == leader) base = atomicAdd(esc_cnt, cntw);
                    base = __shfl(base, leader, 64);
                    if (esc) {
                        int idx = base + pre;
                        if (idx < ESC_CAP) esc_list[idx] = make_int2(i, j);
                    }
                }
            }
            ci += __shfl_xor(ci, 1, 64);
            ci += __shfl_xor(ci, 2, 64);
            ci += __shfl_xor(ci, 4, 64);
            ci += __shfl_xor(ci, 8, 64);
            if (col == 0 && ci) atomicAdd(&cred_i[irow], ci);
        }
    }
    #pragma unroll
    for (int jt = 0; jt < 4; jt++) {
        int v = cj[jt];
        v += __shfl_xor(v, 16, 64);
        v += __shfl_xor(v, 32, 64);
        if (quad == 0 && v) atomicAdd(&cred_j[wj + jt * 16 + col], v);
    }
    __syncthreads();
    if (tid < TM) {
        int i = ib + tid;
        if (i < N_TOT && cred_i[tid]) atomicAdd(&counts[i], cred_i[tid]);
        int j = jb + tid;
        if (j < N_TOT && cred_j[tid]) atomicAdd(&counts[j], cred_j[tid]);
    }
}

// ---------------- fp64 exact recheck of borderline pairs (adds to BOTH ends) ----------------
__global__ void escalate_kernel(const float* __restrict__ feats, const int* __restrict__ ids,
                                const double* __restrict__ sqd,
                                const int* __restrict__ esc_cnt, const int2* __restrict__ esc_list,
                                int* __restrict__ counts) {
    int n = *esc_cnt;
    if (n > ESC_CAP) n = ESC_CAP;
    int lane = threadIdx.x & 63;
    int wglob = (blockIdx.x * blockDim.x + threadIdx.x) >> 6;
    int W = (gridDim.x * blockDim.x) >> 6;
    for (int p = wglob; p < n; p += W) {
        int2 pr = esc_list[p];
        const float* xi = feats + (size_t)ids[pr.x] * D;
        const float* xj = feats + (size_t)ids[pr.y] * D;
        double s = 0.0;
        int k0 = lane * 16;
        #pragma unroll
        for (int k = 0; k < 16; k += 4) {
            float4 a = *(const float4*)(xi + k0 + k);
            float4 b = *(const float4*)(xj + k0 + k);
            s += (double)a.x * b.x + (double)a.y * b.y + (double)a.z * b.z + (double)a.w * b.w;
        }
        #pragma unroll
        for (int off = 32; off > 0; off >>= 1)
            s += __shfl_down(s, off, 64);
        if (lane == 0) {
            double d2 = sqd[pr.x] + sqd[pr.y] - 2.0 * s;
            if (d2 < 0.25) {
                atomicAdd(&counts[pr.x], 1);
                atomicAdd(&counts[pr.y], 1);
            }
        }
    }
}

// ---------------- stable-argsort selection ----------------
__global__ void sel_kernel(const int* __restrict__ counts, const int* __restrict__ ids,
                           int* __restrict__ out_ids, int pcb) {
    int c = blockIdx.x;
    __shared__ int lc[CLS_P];
    for (int p = threadIdx.x; p < CLS_P; p += blockDim.x)
        lc[p] = counts[c * CLS_P + p];
    __syncthreads();
    for (int p = threadIdx.x; p < CLS_P; p += blockDim.x) {
        int cp = lc[p];
        int rank = 0;
        for (int q = 0; q < CLS_P; q++) {
            int cq = lc[q];
            rank += (cq < cp) || (cq == cp && q < p);
        }
        if (rank < pcb)
            out_ids[c * pcb + rank] = ids[c * CLS_P + p];
    }
}

extern "C" void kernel_launch(void* const* d_in, const int* in_sizes, int n_in,
                              void* d_out, int out_size, void* d_ws, size_t ws_size,
                              hipStream_t stream) {
    const float* feats = (const float*)d_in[0];
    const int* ids = (const int*)d_in[1];
    int budget = out_size - N_TOT;
    int pcb = budget / NC;  // 200
    int* out = (int*)d_out;
    int* counts_out = out + NC * pcb;

    char* ws = (char*)d_ws;
    const size_t XH_OFF = 0;
    const size_t SQD_OFF = XH_OFF + (size_t)N_TOT * D * 2;           // 20.48 MB
    const size_t SQF_OFF = SQD_OFF + (size_t)N_TOT * 8;
    const size_t ESCC_OFF = (SQF_OFF + (size_t)N_TOT * 4 + 63) & ~(size_t)63;
    const size_t ESCL_OFF = ESCC_OFF + 64;

    unsigned short* Xh = (unsigned short*)(ws + XH_OFF);
    double* sqd = (double*)(ws + SQD_OFF);
    float* sqf = (float*)(ws + SQF_OFF);
    int* esc_cnt = (int*)(ws + ESCC_OFF);
    int2* esc_list = (int2*)(ws + ESCL_OFF);

    zero_kernel<<<(out_size + 255) / 256, 256, 0, stream>>>(out, out_size, esc_cnt);
    prep_kernel<<<N_TOT, 256, 0, stream>>>(feats, ids, Xh, sqd, sqf);
    dim3 grid((N_TOT + TM - 1) / TM, (N_TOT + TM - 1) / TM);
    count_kernel<<<grid, 256, 0, stream>>>(Xh, sqf, counts_out, esc_cnt, esc_list);
    escalate_kernel<<<2048, 256, 0, stream>>>(feats, ids, sqd, esc_cnt, esc_list, counts_out);
    sel_kernel<<<NC, 256, 0, stream>>>(counts_out, ids, out, pcb);
}

// Round 6
// 1186.572 us; speedup vs baseline: 1.0446x; 1.0446x over previous
//
#include <hip/hip_runtime.h>

#define N_TOT 10000
#define CLS_P 1000
#define NC 10
#define D 1024

#define TM 128            // block tile (i and j)
#define LDT 40            // LDS row stride in halves (32+8): conflict-even for b128 frag reads
#define DELTA 2.5e-5f
#define INV_SCALE2 4.8828125e-4f   // 2 / 4096  (Xh stores 64*x; acc = 4096*dot)
#define ESC_CAP (1 << 22)
#define KCHUNKS (D / 32)

typedef _Float16 f16x8 __attribute__((ext_vector_type(8)));
typedef float f32x4 __attribute__((ext_vector_type(4)));

// ---------------- zero output + escalation counter ----------------
__global__ void zero_kernel(int* __restrict__ out, int n, int* __restrict__ esc_cnt) {
    int i = blockIdx.x * blockDim.x + threadIdx.x;
    if (i < n) out[i] = 0;
    if (i == 0) *esc_cnt = 0;
}

// ---------------- gather + fp16(64x) + fp64 norms ----------------
__global__ void prep_kernel(const float* __restrict__ feats, const int* __restrict__ ids,
                            unsigned short* __restrict__ Xh,
                            double* __restrict__ sqd, float* __restrict__ sqf) {
    int row = blockIdx.x;
    int id = ids[row];
    const float4* rp = (const float4*)(feats + (size_t)id * D);
    float4 v = rp[threadIdx.x];  // 256 threads * 4 = 1024
    float f[4] = {v.x, v.y, v.z, v.w};
    ushort4 hv;
    unsigned short* hp = &hv.x;
    double s = 0.0;
    #pragma unroll
    for (int e = 0; e < 4; e++) {
        s += (double)f[e] * f[e];
        union { _Float16 h; unsigned short u; } cv;
        cv.h = (_Float16)(f[e] * 64.0f);   // RNE; x64 avoids fp16 denormals
        hp[e] = cv.u;
    }
    *(ushort4*)(Xh + (size_t)row * D + threadIdx.x * 4) = hv;

    #pragma unroll
    for (int off = 32; off > 0; off >>= 1)
        s += __shfl_down(s, off, 64);
    __shared__ double wsum[4];
    int lane = threadIdx.x & 63, wv = threadIdx.x >> 6;
    if (lane == 0) wsum[wv] = s;
    __syncthreads();
    if (threadIdx.x == 0) {
        double t = wsum[0] + wsum[1] + wsum[2] + wsum[3];
        sqd[row] = t;
        sqf[row] = (float)t;
    }
}

// ---------------- fp16 MFMA pairwise count (upper-triangle, named-reg dbuf pipeline) ----------------
__launch_bounds__(256, 3)
__global__ void count_kernel(const unsigned short* __restrict__ Xh,
                             const float* __restrict__ sqf,
                             int* __restrict__ counts,
                             int* __restrict__ esc_cnt, int2* __restrict__ esc_list) {
    const int ib = blockIdx.x * TM, jb = blockIdx.y * TM;
    if (jb < ib) return;  // symmetric: only upper triangle of tiles

    // skip tiles that are entirely same-class
    {
        int ci0 = ib / CLS_P, ci1 = (ib + TM - 1) / CLS_P;
        int cj0 = jb / CLS_P, cj1 = (jb + TM - 1) / CLS_P;
        if (ci0 == ci1 && cj0 == cj1 && ci0 == cj0) return;
    }

    __shared__ unsigned short Sa[2 * TM * LDT];   // 20 KB
    __shared__ unsigned short Sb[2 * TM * LDT];   // 20 KB
    __shared__ int cred_i[TM], cred_j[TM];

    const int tid = threadIdx.x;
    const int lane = tid & 63, w = tid >> 6;
    const int wi = (w & 1) * 64, wj = (w >> 1) * 64;
    const int quad = lane >> 4, col = lane & 15;
    const int kq8 = quad * 8;

    // staging mapping: lanes (2k,2k+1) cover row k's 64B chunk
    const int s_row = tid >> 1;           // 0..127
    const int s_kh = (tid & 1) * 16;      // half-offset 0 or 16

    int ga = ib + s_row; if (ga > N_TOT - 1) ga = N_TOT - 1;
    int gb = jb + s_row; if (gb > N_TOT - 1) gb = N_TOT - 1;
    const unsigned short* gpa = Xh + (size_t)ga * D + s_kh;
    const unsigned short* gpb = Xh + (size_t)gb * D + s_kh;

    // two NAMED prefetch register sets (no dynamic indexing -> no scratch)
    uint4 a00, a01, b00, b01;   // phase-even
    uint4 a10, a11, b10, b11;   // phase-odd

#define GLOAD(A0, A1, B0, B1, KC_)                                  \
    {                                                               \
        int kk = (KC_) < KCHUNKS ? (KC_) : KCHUNKS - 1;             \
        const unsigned short* pa = gpa + kk * 32;                   \
        const unsigned short* pb = gpb + kk * 32;                   \
        A0 = *(const uint4*)(pa);                                   \
        A1 = *(const uint4*)(pa + 8);                               \
        B0 = *(const uint4*)(pb);                                   \
        B1 = *(const uint4*)(pb + 8);                               \
    }

#define SWRITE(A0, A1, B0, B1, BUF_)                                \
    {                                                               \
        unsigned short* da = Sa + (BUF_) * (TM * LDT) + s_row * LDT + s_kh; \
        unsigned short* db = Sb + (BUF_) * (TM * LDT) + s_row * LDT + s_kh; \
        *(uint4*)(da) = A0;                                         \
        *(uint4*)(da + 8) = A1;                                     \
        *(uint4*)(db) = B0;                                         \
        *(uint4*)(db + 8) = B1;                                     \
    }

#define FRAGS(BUF_)                                                 \
    {                                                               \
        _Pragma("unroll")                                           \
        for (int t = 0; t < 4; t++) {                               \
            ah[t] = *(const f16x8*)(Sa + (BUF_) * (TM * LDT) + (wi + t * 16 + col) * LDT + kq8); \
            bh[t] = *(const f16x8*)(Sb + (BUF_) * (TM * LDT) + (wj + t * 16 + col) * LDT + kq8); \
        }                                                           \
    }

#define MFMA16                                                      \
    {                                                               \
        _Pragma("unroll")                                           \
        for (int it = 0; it < 4; it++)                              \
            _Pragma("unroll")                                       \
            for (int jt = 0; jt < 4; jt++)                          \
                acc[it][jt] = __builtin_amdgcn_mfma_f32_16x16x32_f16(ah[it], bh[jt], acc[it][jt], 0, 0, 0); \
    }

    f32x4 acc[4][4];
    #pragma unroll
    for (int it = 0; it < 4; it++)
        #pragma unroll
        for (int jt = 0; jt < 4; jt++)
            acc[it][jt] = (f32x4){0.f, 0.f, 0.f, 0.f};

    f16x8 ah[4], bh[4];

    // prologue: buf0 <- kc0 (through even set); odd set <- kc1 (in flight)
    GLOAD(a00, a01, b00, b01, 0);
    SWRITE(a00, a01, b00, b01, 0);
    GLOAD(a10, a11, b10, b11, 1);
    __syncthreads();

    for (int kc = 0; kc < KCHUNKS; kc += 2) {
        // ---- phase A: compute kc from buf0 ----
        GLOAD(a00, a01, b00, b01, kc + 2);      // even set <- kc+2
        FRAGS(0);
        SWRITE(a10, a11, b10, b11, 1);          // buf1 <- kc+1 (waits only odd set)
        __syncthreads();                        // lgkm-only drain
        MFMA16;

        // ---- phase B: compute kc+1 from buf1 ----
        GLOAD(a10, a11, b10, b11, kc + 3);      // odd set <- kc+3
        FRAGS(1);
        SWRITE(a00, a01, b00, b01, 0);          // buf0 <- kc+2 (waits only even set)
        __syncthreads();
        MFMA16;
    }

    // ---------------- epilogue: threshold + ballot-aggregated escalate + symmetric reduce ----------------
    if (tid < TM) { cred_i[tid] = 0; cred_j[tid] = 0; }
    __syncthreads();

    const float thr_lo = 0.25f - DELTA;
    const float thr_hi = 0.25f + DELTA;
    const bool diag = (ib == jb);

    float sqj[4];
    int clsj[4], jv[4], jidx[4];
    #pragma unroll
    for (int jt = 0; jt < 4; jt++) {
        int j = jb + wj + jt * 16 + col;
        jidx[jt] = j;
        jv[jt] = (j < N_TOT);
        sqj[jt] = jv[jt] ? sqf[j] : 0.f;
        clsj[jt] = j / CLS_P;
    }

    int cj[4] = {0, 0, 0, 0};

    #pragma unroll
    for (int it = 0; it < 4; it++) {
        #pragma unroll
        for (int r = 0; r < 4; r++) {
            int irow = wi + it * 16 + quad * 4 + r;
            int i = ib + irow;
            bool iv = (i < N_TOT);
            float sqi = iv ? sqf[i] : 0.f;
            int clsi = i / CLS_P;
            int ci = 0;
            #pragma unroll
            for (int jt = 0; jt < 4; jt++) {
                int j = jidx[jt];
                bool ok = iv && jv[jt] && (clsj[jt] != clsi) && (!diag || j > i);
                float d2 = sqi + sqj[jt] - acc[it][jt][r] * INV_SCALE2;
                bool in = ok && (d2 < thr_lo);
                bool esc = ok && !in && (d2 < thr_hi);
                ci += in ? 1 : 0;
                cj[jt] += in ? 1 : 0;
                unsigned long long m = __ballot(esc);
                if (m) {
                    int leader = __ffsll(m) - 1;
                    int cntw = __popcll(m);
                    int pre = __popcll(m & ((1ull << lane) - 1));
                    int base = 0;
                    if (lane == leader) base = atomicAdd(esc_cnt, cntw);
                    base = __shfl(base, leader, 64);
                    if (esc) {
                        int idx = base + pre;
                        if (idx < ESC_CAP) esc_list[idx] = make_int2(i, j);
                    }
                }
            }
            ci += __shfl_xor(ci, 1, 64);
            ci += __shfl_xor(ci, 2, 64);
            ci += __shfl_xor(ci, 4, 64);
            ci += __shfl_xor(ci, 8, 64);
            if (col == 0 && ci) atomicAdd(&cred_i[irow], ci);
        }
    }
    #pragma unroll
    for (int jt = 0; jt < 4; jt++) {
        int v = cj[jt];
        v += __shfl_xor(v, 16, 64);
        v += __shfl_xor(v, 32, 64);
        if (quad == 0 && v) atomicAdd(&cred_j[wj + jt * 16 + col], v);
    }
    __syncthreads();
    if (tid < TM) {
        int i = ib + tid;
        if (i < N_TOT && cred_i[tid]) atomicAdd(&counts[i], cred_i[tid]);
        int j = jb + tid;
        if (j < N_TOT && cred_j[tid]) atomicAdd(&counts[j], cred_j[tid]);
    }
}

// ---------------- fp64 exact recheck of borderline pairs (adds to BOTH ends) ----------------
__global__ void escalate_kernel(const float* __restrict__ feats, const int* __restrict__ ids,
                                const double* __restrict__ sqd,
                                const int* __restrict__ esc_cnt, const int2* __restrict__ esc_list,
                                int* __restrict__ counts) {
    int n = *esc_cnt;
    if (n > ESC_CAP) n = ESC_CAP;
    int lane = threadIdx.x & 63;
    int wglob = (blockIdx.x * blockDim.x + threadIdx.x) >> 6;
    int W = (gridDim.x * blockDim.x) >> 6;
    for (int p = wglob; p < n; p += W) {
        int2 pr = esc_list[p];
        const float* xi = feats + (size_t)ids[pr.x] * D;
        const float* xj = feats + (size_t)ids[pr.y] * D;
        double s = 0.0;
        int k0 = lane * 16;
        #pragma unroll
        for (int k = 0; k < 16; k += 4) {
            float4 a = *(const float4*)(xi + k0 + k);
            float4 b = *(const float4*)(xj + k0 + k);
            s += (double)a.x * b.x + (double)a.y * b.y + (double)a.z * b.z + (double)a.w * b.w;
        }
        #pragma unroll
        for (int off = 32; off > 0; off >>= 1)
            s += __shfl_down(s, off, 64);
        if (lane == 0) {
            double d2 = sqd[pr.x] + sqd[pr.y] - 2.0 * s;
            if (d2 < 0.25) {
                atomicAdd(&counts[pr.x], 1);
                atomicAdd(&counts[pr.y], 1);
            }
        }
    }
}

// ---------------- stable-argsort selection ----------------
__global__ void sel_kernel(const int* __restrict__ counts, const int* __restrict__ ids,
                           int* __restrict__ out_ids, int pcb) {
    int c = blockIdx.x;
    __shared__ int lc[CLS_P];
    for (int p = threadIdx.x; p < CLS_P; p += blockDim.x)
        lc[p] = counts[c * CLS_P + p];
    __syncthreads();
    for (int p = threadIdx.x; p < CLS_P; p += blockDim.x) {
        int cp = lc[p];
        int rank = 0;
        for (int q = 0; q < CLS_P; q++) {
            int cq = lc[q];
            rank += (cq < cp) || (cq == cp && q < p);
        }
        if (rank < pcb)
            out_ids[c * pcb + rank] = ids[c * CLS_P + p];
    }
}

extern "C" void kernel_launch(void* const* d_in, const int* in_sizes, int n_in,
                              void* d_out, int out_size, void* d_ws, size_t ws_size,
                              hipStream_t stream) {
    const float* feats = (const float*)d_in[0];
    const int* ids = (const int*)d_in[1];
    int budget = out_size - N_TOT;
    int pcb = budget / NC;  // 200
    int* out = (int*)d_out;
    int* counts_out = out + NC * pcb;

    char* ws = (char*)d_ws;
    const size_t XH_OFF = 0;
    const size_t SQD_OFF = XH_OFF + (size_t)N_TOT * D * 2;           // 20.48 MB
    const size_t SQF_OFF = SQD_OFF + (size_t)N_TOT * 8;
    const size_t ESCC_OFF = (SQF_OFF + (size_t)N_TOT * 4 + 63) & ~(size_t)63;
    const size_t ESCL_OFF = ESCC_OFF + 64;

    unsigned short* Xh = (unsigned short*)(ws + XH_OFF);
    double* sqd = (double*)(ws + SQD_OFF);
    float* sqf = (float*)(ws + SQF_OFF);
    int* esc_cnt = (int*)(ws + ESCC_OFF);
    int2* esc_list = (int2*)(ws + ESCL_OFF);

    zero_kernel<<<(out_size + 255) / 256, 256, 0, stream>>>(out, out_size, esc_cnt);
    prep_kernel<<<N_TOT, 256, 0, stream>>>(feats, ids, Xh, sqd, sqf);
    dim3 grid((N_TOT + TM - 1) / TM, (N_TOT + TM - 1) / TM);
    count_kernel<<<grid, 256, 0, stream>>>(Xh, sqf, counts_out, esc_cnt, esc_list);
    escalate_kernel<<<2048, 256, 0, stream>>>(feats, ids, sqd, esc_cnt, esc_list, counts_out);
    sel_kernel<<<NC, 256, 0, stream>>>(counts_out, ids, out, pcb);
}

// Round 7
// 1167.992 us; speedup vs baseline: 1.0612x; 1.0159x over previous
//
#include <hip/hip_runtime.h>

#define N_TOT 10000
#define CLS_P 1000
#define NC 10
#define D 1024

#define TM 128            // block tile (i and j)
#define DELTA 2.5e-5f
#define INV_SCALE2 4.8828125e-4f   // 2 / 4096  (Xh stores 64*x; acc = 4096*dot)
#define ESC_CAP (1 << 22)
#define KCHUNKS (D / 32)

typedef _Float16 f16x8 __attribute__((ext_vector_type(8)));
typedef float f32x4 __attribute__((ext_vector_type(4)));
typedef const __attribute__((address_space(1))) unsigned int* gptr_t;
typedef __attribute__((address_space(3))) unsigned int* lptr_t;

// ---------------- zero output + escalation counter ----------------
__global__ void zero_kernel(int* __restrict__ out, int n, int* __restrict__ esc_cnt) {
    int i = blockIdx.x * blockDim.x + threadIdx.x;
    if (i < n) out[i] = 0;
    if (i == 0) *esc_cnt = 0;
}

// ---------------- gather + fp16(64x) + fp64 norms ----------------
__global__ void prep_kernel(const float* __restrict__ feats, const int* __restrict__ ids,
                            unsigned short* __restrict__ Xh,
                            double* __restrict__ sqd, float* __restrict__ sqf) {
    int row = blockIdx.x;
    int id = ids[row];
    const float4* rp = (const float4*)(feats + (size_t)id * D);
    float4 v = rp[threadIdx.x];  // 256 threads * 4 = 1024
    float f[4] = {v.x, v.y, v.z, v.w};
    ushort4 hv;
    unsigned short* hp = &hv.x;
    double s = 0.0;
    #pragma unroll
    for (int e = 0; e < 4; e++) {
        s += (double)f[e] * f[e];
        union { _Float16 h; unsigned short u; } cv;
        cv.h = (_Float16)(f[e] * 64.0f);   // RNE; x64 avoids fp16 denormals
        hp[e] = cv.u;
    }
    *(ushort4*)(Xh + (size_t)row * D + threadIdx.x * 4) = hv;

    #pragma unroll
    for (int off = 32; off > 0; off >>= 1)
        s += __shfl_down(s, off, 64);
    __shared__ double wsum[4];
    int lane = threadIdx.x & 63, wv = threadIdx.x >> 6;
    if (lane == 0) wsum[wv] = s;
    __syncthreads();
    if (threadIdx.x == 0) {
        double t = wsum[0] + wsum[1] + wsum[2] + wsum[3];
        sqd[row] = t;
        sqf[row] = (float)t;
    }
}

// ---------------- fp16 MFMA pairwise count (triple-buf async, non-draining barrier) ----------------
__launch_bounds__(256, 3)
__global__ void count_kernel(const unsigned short* __restrict__ Xh,
                             const float* __restrict__ sqf,
                             int* __restrict__ counts,
                             int* __restrict__ esc_cnt, int2* __restrict__ esc_list) {
    const int ib = blockIdx.x * TM, jb = blockIdx.y * TM;
    if (jb < ib) return;  // symmetric: only upper triangle of tiles

    // skip tiles that are entirely same-class
    {
        int ci0 = ib / CLS_P, ci1 = (ib + TM - 1) / CLS_P;
        int cj0 = jb / CLS_P, cj1 = (jb + TM - 1) / CLS_P;
        if (ci0 == ci1 && cj0 == cj1 && ci0 == cj0) return;
    }

    // 3 buffers x (A 4096 + B 4096) halves = 48 KB; per-array layout:
    // half-offset = b*1024 + w01*512 + rl0*32 + slot*8   ==  row*32 + slot*8
    __shared__ unsigned short S[3 * 8192];
    __shared__ int cred_i[TM], cred_j[TM];

    const int tid = threadIdx.x;
    const int lane = tid & 63, w = tid >> 6;
    const int wi = (w & 1) * 64, wj = (w >> 1) * 64;
    const int quad = lane >> 4, col = lane & 15;
    const int kq8 = quad * 8;

    // staging: waves 0,1 -> A (rows of ib); waves 2,3 -> B (rows of jb)
    const int warr = w >> 1;
    const int w01 = w & 1;
    const int rl0 = lane >> 2;      // 0..15 row within 16-row call group
    const int slot = lane & 3;      // dest k-slot
    const int q = (slot - rl0 - (rl0 >> 2)) & 3;   // source k-quarter (swizzle)
    const int rowbase = warr ? jb : ib;

    const unsigned short* src[4];
    #pragma unroll
    for (int b = 0; b < 4; b++) {
        int grow = rowbase + b * 32 + w01 * 16 + rl0;
        if (grow > N_TOT - 1) grow = N_TOT - 1;
        src[b] = Xh + (size_t)grow * D + q * 8;
    }

#define STAGE(KC_, BUFBASE_)                                                     \
    {                                                                            \
        _Pragma("unroll")                                                        \
        for (int b = 0; b < 4; b++) {                                            \
            __builtin_amdgcn_global_load_lds(                                    \
                (gptr_t)(src[b] + (KC_) * 32),                                   \
                (lptr_t)((BUFBASE_) + warr * 4096 + b * 1024 + w01 * 512),       \
                16, 0, 0);                                                       \
        }                                                                        \
    }

#define FRAGS(BUFBASE_)                                                          \
    {                                                                            \
        _Pragma("unroll")                                                        \
        for (int t = 0; t < 4; t++) {                                            \
            int rA = wi + t * 16 + col;                                          \
            int sA = (quad + rA + (rA >> 2)) & 3;                                \
            ah[t] = *(const f16x8*)((BUFBASE_) + rA * 32 + sA * 8);              \
            int rB = wj + t * 16 + col;                                          \
            int sB = (quad + rB + (rB >> 2)) & 3;                                \
            bh[t] = *(const f16x8*)((BUFBASE_) + 4096 + rB * 32 + sB * 8);       \
        }                                                                        \
    }

#define MFMA16                                                                   \
    {                                                                            \
        _Pragma("unroll")                                                        \
        for (int it = 0; it < 4; it++)                                           \
            _Pragma("unroll")                                                    \
            for (int jt = 0; jt < 4; jt++)                                       \
                acc[it][jt] = __builtin_amdgcn_mfma_f32_16x16x32_f16(ah[it], bh[jt], acc[it][jt], 0, 0, 0); \
    }

    f32x4 acc[4][4];
    #pragma unroll
    for (int it = 0; it < 4; it++)
        #pragma unroll
        for (int jt = 0; jt < 4; jt++)
            acc[it][jt] = (f32x4){0.f, 0.f, 0.f, 0.f};

    f16x8 ah[4], bh[4];

    unsigned short* b0 = S;
    unsigned short* b1 = S + 8192;
    unsigned short* b2 = S + 16384;

    // prologue: kc0 -> b0, kc1 -> b1 (8 loads in flight), wait only for kc0
    STAGE(0, b0);
    STAGE(1, b1);
    asm volatile("s_waitcnt vmcnt(4) lgkmcnt(0)\ns_barrier" ::: "memory");

    for (int kc = 0; kc < KCHUNKS; kc++) {
        if (kc + 2 < KCHUNKS) {
            STAGE(kc + 2, b2);
            FRAGS(b0);
            // wait only for the stage issued LAST iteration (kc+1, consumed next iter);
            // this iteration's 4 loads stay in flight across the barrier
            asm volatile("s_waitcnt vmcnt(4) lgkmcnt(0)\ns_barrier" ::: "memory");
        } else {
            FRAGS(b0);
            asm volatile("s_waitcnt vmcnt(0) lgkmcnt(0)\ns_barrier" ::: "memory");
        }
        MFMA16;
        unsigned short* t = b0; b0 = b1; b1 = b2; b2 = t;
    }

    // ---------------- epilogue: threshold + ballot-aggregated escalate + symmetric reduce ----------------
    if (tid < TM) { cred_i[tid] = 0; cred_j[tid] = 0; }
    __syncthreads();

    const float thr_lo = 0.25f - DELTA;
    const float thr_hi = 0.25f + DELTA;
    const bool diag = (ib == jb);

    float sqj[4];
    int clsj[4], jv[4], jidx[4];
    #pragma unroll
    for (int jt = 0; jt < 4; jt++) {
        int j = jb + wj + jt * 16 + col;
        jidx[jt] = j;
        jv[jt] = (j < N_TOT);
        sqj[jt] = jv[jt] ? sqf[j] : 0.f;
        clsj[jt] = j / CLS_P;
    }

    int cj[4] = {0, 0, 0, 0};

    #pragma unroll
    for (int it = 0; it < 4; it++) {
        #pragma unroll
        for (int r = 0; r < 4; r++) {
            int irow = wi + it * 16 + quad * 4 + r;
            int i = ib + irow;
            bool iv = (i < N_TOT);
            float sqi = iv ? sqf[i] : 0.f;
            int clsi = i / CLS_P;
            int ci = 0;
            #pragma unroll
            for (int jt = 0; jt < 4; jt++) {
                int j = jidx[jt];
                bool ok = iv && jv[jt] && (clsj[jt] != clsi) && (!diag || j > i);
                float d2 = sqi + sqj[jt] - acc[it][jt][r] * INV_SCALE2;
                bool in = ok && (d2 < thr_lo);
                bool esc = ok && !in && (d2 < thr_hi);
                ci += in ? 1 : 0;
                cj[jt] += in ? 1 : 0;
                unsigned long long m = __ballot(esc);
                if (m) {
                    int leader = __ffsll(m) - 1;
                    int cntw = __popcll(m);
                    int pre = __popcll(m & ((1ull << lane) - 1));
                    int base = 0;
                    if (lane == leader) base = atomicAdd(esc_cnt, cntw);
                    base = __shfl(base, leader, 64);
                    if (esc) {
                        int idx = base + pre;
                        if (idx < ESC_CAP) esc_list[idx] = make_int2(i, j);
                    }
                }
            }
            ci += __shfl_xor(ci, 1, 64);
            ci += __shfl_xor(ci, 2, 64);
            ci += __shfl_xor(ci, 4, 64);
            ci += __shfl_xor(ci, 8, 64);
            if (col == 0 && ci) atomicAdd(&cred_i[irow], ci);
        }
    }
    #pragma unroll
    for (int jt = 0; jt < 4; jt++) {
        int v = cj[jt];
        v += __shfl_xor(v, 16, 64);
        v += __shfl_xor(v, 32, 64);
        if (quad == 0 && v) atomicAdd(&cred_j[wj + jt * 16 + col], v);
    }
    __syncthreads();
    if (tid < TM) {
        int i = ib + tid;
        if (i < N_TOT && cred_i[tid]) atomicAdd(&counts[i], cred_i[tid]);
        int j = jb + tid;
        if (j < N_TOT && cred_j[tid]) atomicAdd(&counts[j], cred_j[tid]);
    }
}

// ---------------- fp64 exact recheck: 16 lanes per pair, 4 pairs per wave ----------------
__global__ void escalate_kernel(const float* __restrict__ feats, const int* __restrict__ ids,
                                const double* __restrict__ sqd,
                                const int* __restrict__ esc_cnt, const int2* __restrict__ esc_list,
                                int* __restrict__ counts) {
    int n = *esc_cnt;
    if (n > ESC_CAP) n = ESC_CAP;
    int lane = threadIdx.x & 63;
    int sub = lane >> 4;         // pair slot within wave
    int l16 = lane & 15;
    int wglob = (blockIdx.x * blockDim.x + threadIdx.x) >> 6;
    int W = (gridDim.x * blockDim.x) >> 6;
    for (int p0 = wglob * 4; p0 < n; p0 += W * 4) {
        int p = p0 + sub;
        bool act = (p < n);
        int2 pr = act ? esc_list[p] : make_int2(0, 0);
        const float* xi = feats + (size_t)ids[pr.x] * D;
        const float* xj = feats + (size_t)ids[pr.y] * D;
        double s = 0.0;
        int k0 = l16 * 64;
        #pragma unroll
        for (int k = 0; k < 64; k += 4) {
            float4 a = *(const float4*)(xi + k0 + k);
            float4 b = *(const float4*)(xj + k0 + k);
            s += (double)a.x * b.x + (double)a.y * b.y + (double)a.z * b.z + (double)a.w * b.w;
        }
        s += __shfl_xor(s, 1, 64);
        s += __shfl_xor(s, 2, 64);
        s += __shfl_xor(s, 4, 64);
        s += __shfl_xor(s, 8, 64);
        if (act && l16 == 0) {
            double d2 = sqd[pr.x] + sqd[pr.y] - 2.0 * s;
            if (d2 < 0.25) {
                atomicAdd(&counts[pr.x], 1);
                atomicAdd(&counts[pr.y], 1);
            }
        }
    }
}

// ---------------- stable-argsort selection (one thread per p) ----------------
__global__ void sel_kernel(const int* __restrict__ counts, const int* __restrict__ ids,
                           int* __restrict__ out_ids, int pcb) {
    int c = blockIdx.x;
    __shared__ int lc[CLS_P];
    for (int p = threadIdx.x; p < CLS_P; p += blockDim.x)
        lc[p] = counts[c * CLS_P + p];
    __syncthreads();
    int p = threadIdx.x;
    if (p < CLS_P) {
        int cp = lc[p];
        int rank = 0;
        for (int qq = 0; qq < CLS_P; qq++) {
            int cq = lc[qq];
            rank += (cq < cp) || (cq == cp && qq < p);
        }
        if (rank < pcb)
            out_ids[c * pcb + rank] = ids[c * CLS_P + p];
    }
}

extern "C" void kernel_launch(void* const* d_in, const int* in_sizes, int n_in,
                              void* d_out, int out_size, void* d_ws, size_t ws_size,
                              hipStream_t stream) {
    const float* feats = (const float*)d_in[0];
    const int* ids = (const int*)d_in[1];
    int budget = out_size - N_TOT;
    int pcb = budget / NC;  // 200
    int* out = (int*)d_out;
    int* counts_out = out + NC * pcb;

    char* ws = (char*)d_ws;
    const size_t XH_OFF = 0;
    const size_t SQD_OFF = XH_OFF + (size_t)N_TOT * D * 2;           // 20.48 MB
    const size_t SQF_OFF = SQD_OFF + (size_t)N_TOT * 8;
    const size_t ESCC_OFF = (SQF_OFF + (size_t)N_TOT * 4 + 63) & ~(size_t)63;
    const size_t ESCL_OFF = ESCC_OFF + 64;

    unsigned short* Xh = (unsigned short*)(ws + XH_OFF);
    double* sqd = (double*)(ws + SQD_OFF);
    float* sqf = (float*)(ws + SQF_OFF);
    int* esc_cnt = (int*)(ws + ESCC_OFF);
    int2* esc_list = (int2*)(ws + ESCL_OFF);

    zero_kernel<<<(out_size + 255) / 256, 256, 0, stream>>>(out, out_size, esc_cnt);
    prep_kernel<<<N_TOT, 256, 0, stream>>>(feats, ids, Xh, sqd, sqf);
    dim3 grid((N_TOT + TM - 1) / TM, (N_TOT + TM - 1) / TM);
    count_kernel<<<grid, 256, 0, stream>>>(Xh, sqf, counts_out, esc_cnt, esc_list);
    escalate_kernel<<<4096, 256, 0, stream>>>(feats, ids, sqd, esc_cnt, esc_list, counts_out);
    sel_kernel<<<NC, 1024, 0, stream>>>(counts_out, ids, out, pcb);
}

// Round 8
// 434.042 us; speedup vs baseline: 2.8556x; 2.6910x over previous
//
#include <hip/hip_runtime.h>

#define N_TOT 10000
#define CLS_P 1000
#define NC 10
#define D 1024

#define TM 128            // block tile (i and j)
#define DELTA 2.5e-5f
#define INV_SCALE2 4.8828125e-4f   // 2 / 4096  (Xh stores 64*x; acc = 4096*dot)
#define ESC_CAP (1 << 22)
#define ESC_LOC 512
#define KCHUNKS (D / 32)
#define NTILE ((N_TOT + TM - 1) / TM)   // 79

typedef _Float16 f16x8 __attribute__((ext_vector_type(8)));
typedef float f32x4 __attribute__((ext_vector_type(4)));
typedef const __attribute__((address_space(1))) unsigned int* gptr_t;
typedef __attribute__((address_space(3))) unsigned int* lptr_t;

// ---------------- zero output + escalation counter ----------------
__global__ void zero_kernel(int* __restrict__ out, int n, int* __restrict__ esc_cnt) {
    int i = blockIdx.x * blockDim.x + threadIdx.x;
    if (i < n) out[i] = 0;
    if (i == 0) *esc_cnt = 0;
}

// ---------------- gather + fp16(64x) + fp64 norms ----------------
__global__ void prep_kernel(const float* __restrict__ feats, const int* __restrict__ ids,
                            unsigned short* __restrict__ Xh,
                            double* __restrict__ sqd, float* __restrict__ sqf) {
    int row = blockIdx.x;
    int id = ids[row];
    const float4* rp = (const float4*)(feats + (size_t)id * D);
    float4 v = rp[threadIdx.x];  // 256 threads * 4 = 1024
    float f[4] = {v.x, v.y, v.z, v.w};
    ushort4 hv;
    unsigned short* hp = &hv.x;
    double s = 0.0;
    #pragma unroll
    for (int e = 0; e < 4; e++) {
        s += (double)f[e] * f[e];
        union { _Float16 h; unsigned short u; } cv;
        cv.h = (_Float16)(f[e] * 64.0f);   // RNE; x64 avoids fp16 denormals
        hp[e] = cv.u;
    }
    *(ushort4*)(Xh + (size_t)row * D + threadIdx.x * 4) = hv;

    #pragma unroll
    for (int off = 32; off > 0; off >>= 1)
        s += __shfl_down(s, off, 64);
    __shared__ double wsum[4];
    int lane = threadIdx.x & 63, wv = threadIdx.x >> 6;
    if (lane == 0) wsum[wv] = s;
    __syncthreads();
    if (threadIdx.x == 0) {
        double t = wsum[0] + wsum[1] + wsum[2] + wsum[3];
        sqd[row] = t;
        sqf[row] = (float)t;
    }
}

// ---------------- fp16 MFMA pairwise count (quad-buf async, LDS-buffered escalation) ----------------
__launch_bounds__(256, 2)
__global__ void count_kernel(const unsigned short* __restrict__ Xh,
                             const float* __restrict__ sqf,
                             int* __restrict__ counts,
                             int* __restrict__ esc_cnt, int2* __restrict__ esc_list) {
    // ---- band swizzle: 8 i-tiles per band, j fastest -> L2-local working set ----
    int bid = blockIdx.y * gridDim.x + blockIdx.x;
    int it_t = 0, jt_t = 0;
    {
        int rem = bid, band = 0;
        while (true) {
            int h = NTILE - band * 8; if (h > 8) h = 8;
            int area = h * NTILE;
            if (rem < area) { it_t = band * 8 + rem % h; jt_t = rem / h; break; }
            rem -= area; band++;
        }
    }
    const int ib = it_t * TM, jb = jt_t * TM;
    if (jb < ib) return;  // symmetric: only upper triangle of tiles

    // skip tiles that are entirely same-class
    {
        int ci0 = ib / CLS_P, ci1 = (ib + TM - 1) / CLS_P;
        int cj0 = jb / CLS_P, cj1 = (jb + TM - 1) / CLS_P;
        if (ci0 == ci1 && cj0 == cj1 && ci0 == cj0) return;
    }

    // 4 buffers x (A 8KB + B 8KB) = 64 KB
    __shared__ unsigned short S[4 * 8192];
    __shared__ int cred_i[TM], cred_j[TM];
    __shared__ int esc_n, esc_base;
    __shared__ int2 esc_buf[ESC_LOC];

    const int tid = threadIdx.x;
    const int lane = tid & 63, w = tid >> 6;
    const int wi = (w & 1) * 64, wj = (w >> 1) * 64;
    const int quad = lane >> 4, col = lane & 15;

    if (tid == 0) esc_n = 0;

    // staging: waves 0,1 -> A (rows of ib); waves 2,3 -> B (rows of jb)
    const int warr = w >> 1;
    const int w01 = w & 1;
    const int rl0 = lane >> 2;      // 0..15 row within 16-row call group
    const int slot = lane & 3;      // dest k-slot
    const int q = (slot - rl0 - (rl0 >> 2)) & 3;   // source k-quarter (swizzle)
    const int rowbase = warr ? jb : ib;

    const unsigned short* src[4];
    #pragma unroll
    for (int b = 0; b < 4; b++) {
        int grow = rowbase + b * 32 + w01 * 16 + rl0;
        if (grow > N_TOT - 1) grow = N_TOT - 1;
        src[b] = Xh + (size_t)grow * D + q * 8;
    }

#define STAGE(KC_, BUFBASE_)                                                     \
    {                                                                            \
        _Pragma("unroll")                                                        \
        for (int b = 0; b < 4; b++) {                                            \
            __builtin_amdgcn_global_load_lds(                                    \
                (gptr_t)(src[b] + (KC_) * 32),                                   \
                (lptr_t)((BUFBASE_) + warr * 4096 + b * 1024 + w01 * 512),       \
                16, 0, 0);                                                       \
        }                                                                        \
    }

#define FRAGS(BUFBASE_)                                                          \
    {                                                                            \
        _Pragma("unroll")                                                        \
        for (int t = 0; t < 4; t++) {                                            \
            int rA = wi + t * 16 + col;                                          \
            int sA = (quad + rA + (rA >> 2)) & 3;                                \
            ah[t] = *(const f16x8*)((BUFBASE_) + rA * 32 + sA * 8);              \
            int rB = wj + t * 16 + col;                                          \
            int sB = (quad + rB + (rB >> 2)) & 3;                                \
            bh[t] = *(const f16x8*)((BUFBASE_) + 4096 + rB * 32 + sB * 8);       \
        }                                                                        \
    }

#define MFMA16                                                                   \
    {                                                                            \
        _Pragma("unroll")                                                        \
        for (int it = 0; it < 4; it++)                                           \
            _Pragma("unroll")                                                    \
            for (int jt = 0; jt < 4; jt++)                                       \
                acc[it][jt] = __builtin_amdgcn_mfma_f32_16x16x32_f16(ah[it], bh[jt], acc[it][jt], 0, 0, 0); \
    }

    f32x4 acc[4][4];
    #pragma unroll
    for (int it = 0; it < 4; it++)
        #pragma unroll
        for (int jt = 0; jt < 4; jt++)
            acc[it][jt] = (f32x4){0.f, 0.f, 0.f, 0.f};

    f16x8 ah[4], bh[4];

    unsigned short* p0 = S;
    unsigned short* p1 = S + 8192;
    unsigned short* p2 = S + 16384;
    unsigned short* p3 = S + 24576;

    // prologue: kc0..kc2 staged (12 loads in flight); wait only kc0 (leave 8)
    STAGE(0, p0);
    STAGE(1, p1);
    STAGE(2, p2);
    asm volatile("s_waitcnt vmcnt(8) lgkmcnt(0)\ns_barrier" ::: "memory");

    for (int kc = 0; kc < KCHUNKS; kc++) {
        if (kc + 3 < KCHUNKS) STAGE(kc + 3, p3);
        FRAGS(p0);
        // retire the chunk needed NEXT iteration; keep newer stages in flight
        if (kc + 3 < KCHUNKS) {
            asm volatile("s_waitcnt vmcnt(8) lgkmcnt(0)\ns_barrier" ::: "memory");
        } else if (kc + 2 < KCHUNKS) {
            asm volatile("s_waitcnt vmcnt(4) lgkmcnt(0)\ns_barrier" ::: "memory");
        } else {
            asm volatile("s_waitcnt vmcnt(0) lgkmcnt(0)\ns_barrier" ::: "memory");
        }
        MFMA16;
        unsigned short* t = p0; p0 = p1; p1 = p2; p2 = p3; p3 = t;
    }

    // ---------------- epilogue: threshold + LDS-buffered escalate + symmetric reduce ----------------
    if (tid < TM) { cred_i[tid] = 0; cred_j[tid] = 0; }
    __syncthreads();

    const float thr_lo = 0.25f - DELTA;
    const float thr_hi = 0.25f + DELTA;
    const bool diag = (ib == jb);

    float sqj[4];
    int clsj[4], jv[4], jidx[4];
    #pragma unroll
    for (int jt = 0; jt < 4; jt++) {
        int j = jb + wj + jt * 16 + col;
        jidx[jt] = j;
        jv[jt] = (j < N_TOT);
        sqj[jt] = jv[jt] ? sqf[j] : 0.f;
        clsj[jt] = j / CLS_P;
    }

    int cj[4] = {0, 0, 0, 0};

    #pragma unroll
    for (int it = 0; it < 4; it++) {
        #pragma unroll
        for (int r = 0; r < 4; r++) {
            int irow = wi + it * 16 + quad * 4 + r;
            int i = ib + irow;
            bool iv = (i < N_TOT);
            float sqi = iv ? sqf[i] : 0.f;
            int clsi = i / CLS_P;
            int ci = 0;
            #pragma unroll
            for (int jt = 0; jt < 4; jt++) {
                int j = jidx[jt];
                bool ok = iv && jv[jt] && (clsj[jt] != clsi) && (!diag || j > i);
                float d2 = sqi + sqj[jt] - acc[it][jt][r] * INV_SCALE2;
                bool in = ok && (d2 < thr_lo);
                bool esc = ok && !in && (d2 < thr_hi);
                ci += in ? 1 : 0;
                cj[jt] += in ? 1 : 0;
                if (esc) {
                    int k = atomicAdd(&esc_n, 1);      // LDS atomic: fast
                    if (k < ESC_LOC) {
                        esc_buf[k] = make_int2(i, j);
                    } else {
                        int idx = atomicAdd(esc_cnt, 1);   // rare overflow path
                        if (idx < ESC_CAP) esc_list[idx] = make_int2(i, j);
                    }
                }
            }
            ci += __shfl_xor(ci, 1, 64);
            ci += __shfl_xor(ci, 2, 64);
            ci += __shfl_xor(ci, 4, 64);
            ci += __shfl_xor(ci, 8, 64);
            if (col == 0 && ci) atomicAdd(&cred_i[irow], ci);
        }
    }
    #pragma unroll
    for (int jt = 0; jt < 4; jt++) {
        int v = cj[jt];
        v += __shfl_xor(v, 16, 64);
        v += __shfl_xor(v, 32, 64);
        if (quad == 0 && v) atomicAdd(&cred_j[wj + jt * 16 + col], v);
    }
    __syncthreads();
    if (tid < TM) {
        int i = ib + tid;
        if (i < N_TOT && cred_i[tid]) atomicAdd(&counts[i], cred_i[tid]);
        int j = jb + tid;
        if (j < N_TOT && cred_j[tid]) atomicAdd(&counts[j], cred_j[tid]);
    }
    // flush escalation buffer: ONE global atomic per block
    if (tid == 0) {
        int n = esc_n; if (n > ESC_LOC) n = ESC_LOC;
        esc_n = n;
        esc_base = atomicAdd(esc_cnt, n);
    }
    __syncthreads();
    for (int k = tid; k < esc_n; k += 256) {
        int idx = esc_base + k;
        if (idx < ESC_CAP) esc_list[idx] = esc_buf[k];
    }
}

// ---------------- fp64 exact recheck: 16 lanes per pair, 4 pairs per wave ----------------
__global__ void escalate_kernel(const float* __restrict__ feats, const int* __restrict__ ids,
                                const double* __restrict__ sqd,
                                const int* __restrict__ esc_cnt, const int2* __restrict__ esc_list,
                                int* __restrict__ counts) {
    int n = *esc_cnt;
    if (n > ESC_CAP) n = ESC_CAP;
    int lane = threadIdx.x & 63;
    int sub = lane >> 4;         // pair slot within wave
    int l16 = lane & 15;
    int wglob = (blockIdx.x * blockDim.x + threadIdx.x) >> 6;
    int W = (gridDim.x * blockDim.x) >> 6;
    for (int p0 = wglob * 4; p0 < n; p0 += W * 4) {
        int p = p0 + sub;
        bool act = (p < n);
        int2 pr = act ? esc_list[p] : make_int2(0, 0);
        const float* xi = feats + (size_t)ids[pr.x] * D;
        const float* xj = feats + (size_t)ids[pr.y] * D;
        double s = 0.0;
        int k0 = l16 * 64;
        #pragma unroll
        for (int k = 0; k < 64; k += 4) {
            float4 a = *(const float4*)(xi + k0 + k);
            float4 b = *(const float4*)(xj + k0 + k);
            s += (double)a.x * b.x + (double)a.y * b.y + (double)a.z * b.z + (double)a.w * b.w;
        }
        s += __shfl_xor(s, 1, 64);
        s += __shfl_xor(s, 2, 64);
        s += __shfl_xor(s, 4, 64);
        s += __shfl_xor(s, 8, 64);
        if (act && l16 == 0) {
            double d2 = sqd[pr.x] + sqd[pr.y] - 2.0 * s;
            if (d2 < 0.25) {
                atomicAdd(&counts[pr.x], 1);
                atomicAdd(&counts[pr.y], 1);
            }
        }
    }
}

// ---------------- stable-argsort selection (one thread per p) ----------------
__global__ void sel_kernel(const int* __restrict__ counts, const int* __restrict__ ids,
                           int* __restrict__ out_ids, int pcb) {
    int c = blockIdx.x;
    __shared__ int lc[CLS_P];
    for (int p = threadIdx.x; p < CLS_P; p += blockDim.x)
        lc[p] = counts[c * CLS_P + p];
    __syncthreads();
    int p = threadIdx.x;
    if (p < CLS_P) {
        int cp = lc[p];
        int rank = 0;
        for (int qq = 0; qq < CLS_P; qq++) {
            int cq = lc[qq];
            rank += (cq < cp) || (cq == cp && qq < p);
        }
        if (rank < pcb)
            out_ids[c * pcb + rank] = ids[c * CLS_P + p];
    }
}

extern "C" void kernel_launch(void* const* d_in, const int* in_sizes, int n_in,
                              void* d_out, int out_size, void* d_ws, size_t ws_size,
                              hipStream_t stream) {
    const float* feats = (const float*)d_in[0];
    const int* ids = (const int*)d_in[1];
    int budget = out_size - N_TOT;
    int pcb = budget / NC;  // 200
    int* out = (int*)d_out;
    int* counts_out = out + NC * pcb;

    char* ws = (char*)d_ws;
    const size_t XH_OFF = 0;
    const size_t SQD_OFF = XH_OFF + (size_t)N_TOT * D * 2;           // 20.48 MB
    const size_t SQF_OFF = SQD_OFF + (size_t)N_TOT * 8;
    const size_t ESCC_OFF = (SQF_OFF + (size_t)N_TOT * 4 + 63) & ~(size_t)63;
    const size_t ESCL_OFF = ESCC_OFF + 64;

    unsigned short* Xh = (unsigned short*)(ws + XH_OFF);
    double* sqd = (double*)(ws + SQD_OFF);
    float* sqf = (float*)(ws + SQF_OFF);
    int* esc_cnt = (int*)(ws + ESCC_OFF);
    int2* esc_list = (int2*)(ws + ESCL_OFF);

    zero_kernel<<<(out_size + 255) / 256, 256, 0, stream>>>(out, out_size, esc_cnt);
    prep_kernel<<<N_TOT, 256, 0, stream>>>(feats, ids, Xh, sqd, sqf);
    dim3 grid(NTILE, NTILE);
    count_kernel<<<grid, 256, 0, stream>>>(Xh, sqf, counts_out, esc_cnt, esc_list);
    escalate_kernel<<<4096, 256, 0, stream>>>(feats, ids, sqd, esc_cnt, esc_list, counts_out);
    sel_kernel<<<NC, 1024, 0, stream>>>(counts_out, ids, out, pcb);
}

// Round 9
// 362.659 us; speedup vs baseline: 3.4177x; 1.1968x over previous
//
#include <hip/hip_runtime.h>

#define N_TOT 10000
#define CLS_P 1000
#define NC 10
#define D 1024

#define TM 128            // block tile (i and j)
#define DELTA 1.6e-5f
#define INV_SCALE2 4.8828125e-4f   // 2 / 4096  (Xh stores 64*x; acc = 4096*dot)
#define ESC_CAP (1 << 22)
#define ESC_LOC 256
#define KCHUNKS (D / 32)
#define NTILE ((N_TOT + TM - 1) / TM)   // 79

typedef _Float16 f16x8 __attribute__((ext_vector_type(8)));
typedef float f32x4 __attribute__((ext_vector_type(4)));
typedef const __attribute__((address_space(1))) unsigned int* gptr_t;
typedef __attribute__((address_space(3))) unsigned int* lptr_t;

// ---------------- zero output + escalation counter ----------------
__global__ void zero_kernel(int* __restrict__ out, int n, int* __restrict__ esc_cnt) {
    int i = blockIdx.x * blockDim.x + threadIdx.x;
    if (i < n) out[i] = 0;
    if (i == 0) *esc_cnt = 0;
}

// ---------------- gather + fp16(64x) + fp64 norms ----------------
__global__ void prep_kernel(const float* __restrict__ feats, const int* __restrict__ ids,
                            unsigned short* __restrict__ Xh,
                            double* __restrict__ sqd, float* __restrict__ sqf) {
    int row = blockIdx.x;
    int id = ids[row];
    const float4* rp = (const float4*)(feats + (size_t)id * D);
    float4 v = rp[threadIdx.x];  // 256 threads * 4 = 1024
    float f[4] = {v.x, v.y, v.z, v.w};
    ushort4 hv;
    unsigned short* hp = &hv.x;
    double s = 0.0;
    #pragma unroll
    for (int e = 0; e < 4; e++) {
        s += (double)f[e] * f[e];
        union { _Float16 h; unsigned short u; } cv;
        cv.h = (_Float16)(f[e] * 64.0f);   // RNE; x64 avoids fp16 denormals
        hp[e] = cv.u;
    }
    *(ushort4*)(Xh + (size_t)row * D + threadIdx.x * 4) = hv;

    #pragma unroll
    for (int off = 32; off > 0; off >>= 1)
        s += __shfl_down(s, off, 64);
    __shared__ double wsum[4];
    int lane = threadIdx.x & 63, wv = threadIdx.x >> 6;
    if (lane == 0) wsum[wv] = s;
    __syncthreads();
    if (threadIdx.x == 0) {
        double t = wsum[0] + wsum[1] + wsum[2] + wsum[3];
        sqd[row] = t;
        sqf[row] = (float)t;
    }
}

// ---------------- fp16 MFMA pairwise count (3-buf async, LDS-buffered escalation) ----------------
__launch_bounds__(256, 3)
__global__ void count_kernel(const unsigned short* __restrict__ Xh,
                             const float* __restrict__ sqf,
                             int* __restrict__ counts,
                             int* __restrict__ esc_cnt, int2* __restrict__ esc_list) {
    // ---- band swizzle: 8 i-tiles per band, j fastest -> L2-local working set ----
    int bid = blockIdx.y * gridDim.x + blockIdx.x;
    int it_t = 0, jt_t = 0;
    {
        int rem = bid, band = 0;
        while (true) {
            int h = NTILE - band * 8; if (h > 8) h = 8;
            int area = h * NTILE;
            if (rem < area) { it_t = band * 8 + rem % h; jt_t = rem / h; break; }
            rem -= area; band++;
        }
    }
    const int ib = it_t * TM, jb = jt_t * TM;
    if (jb < ib) return;  // symmetric: only upper triangle of tiles

    // skip tiles that are entirely same-class
    {
        int ci0 = ib / CLS_P, ci1 = (ib + TM - 1) / CLS_P;
        int cj0 = jb / CLS_P, cj1 = (jb + TM - 1) / CLS_P;
        if (ci0 == ci1 && cj0 == cj1 && ci0 == cj0) return;
    }

    // 3 buffers x (A 8KB + B 8KB) = 48 KB
    __shared__ unsigned short S[3 * 8192];
    __shared__ int cred_i[TM], cred_j[TM];
    __shared__ int esc_n, esc_base;
    __shared__ int2 esc_buf[ESC_LOC];

    const int tid = threadIdx.x;
    const int lane = tid & 63, w = tid >> 6;
    const int wi = (w & 1) * 64, wj = (w >> 1) * 64;
    const int quad = lane >> 4, col = lane & 15;

    if (tid == 0) esc_n = 0;

    // staging: waves 0,1 -> A (rows of ib); waves 2,3 -> B (rows of jb)
    const int warr = w >> 1;
    const int w01 = w & 1;
    const int rl0 = lane >> 2;      // 0..15 row within 16-row call group
    const int slot = lane & 3;      // dest k-slot
    const int q = (slot - rl0 - (rl0 >> 2)) & 3;   // source k-quarter (swizzle)
    const int rowbase = warr ? jb : ib;

    const unsigned short* src[4];
    #pragma unroll
    for (int b = 0; b < 4; b++) {
        int grow = rowbase + b * 32 + w01 * 16 + rl0;
        if (grow > N_TOT - 1) grow = N_TOT - 1;
        src[b] = Xh + (size_t)grow * D + q * 8;
    }

#define STAGE(KC_, BUFBASE_)                                                     \
    {                                                                            \
        _Pragma("unroll")                                                        \
        for (int b = 0; b < 4; b++) {                                            \
            __builtin_amdgcn_global_load_lds(                                    \
                (gptr_t)(src[b] + (KC_) * 32),                                   \
                (lptr_t)((BUFBASE_) + warr * 4096 + b * 1024 + w01 * 512),       \
                16, 0, 0);                                                       \
        }                                                                        \
    }

#define FRAGS(BUFBASE_)                                                          \
    {                                                                            \
        _Pragma("unroll")                                                        \
        for (int t = 0; t < 4; t++) {                                            \
            int rA = wi + t * 16 + col;                                          \
            int sA = (quad + rA + (rA >> 2)) & 3;                                \
            ah[t] = *(const f16x8*)((BUFBASE_) + rA * 32 + sA * 8);              \
            int rB = wj + t * 16 + col;                                          \
            int sB = (quad + rB + (rB >> 2)) & 3;                                \
            bh[t] = *(const f16x8*)((BUFBASE_) + 4096 + rB * 32 + sB * 8);       \
        }                                                                        \
    }

#define MFMA16                                                                   \
    {                                                                            \
        _Pragma("unroll")                                                        \
        for (int it = 0; it < 4; it++)                                           \
            _Pragma("unroll")                                                    \
            for (int jt = 0; jt < 4; jt++)                                       \
                acc[it][jt] = __builtin_amdgcn_mfma_f32_16x16x32_f16(ah[it], bh[jt], acc[it][jt], 0, 0, 0); \
    }

    f32x4 acc[4][4];
    #pragma unroll
    for (int it = 0; it < 4; it++)
        #pragma unroll
        for (int jt = 0; jt < 4; jt++)
            acc[it][jt] = (f32x4){0.f, 0.f, 0.f, 0.f};

    f16x8 ah[4], bh[4];

    unsigned short* p0 = S;
    unsigned short* p1 = S + 8192;
    unsigned short* p2 = S + 16384;

    // prologue: kc0 -> p0, kc1 -> p1 (8 loads in flight); wait only kc0
    STAGE(0, p0);
    STAGE(1, p1);
    asm volatile("s_waitcnt vmcnt(4) lgkmcnt(0)\ns_barrier" ::: "memory");

    for (int kc = 0; kc < KCHUNKS; kc++) {
        if (kc + 2 < KCHUNKS) STAGE(kc + 2, p2);
        FRAGS(p0);
        // retire the chunk needed NEXT iteration; keep the newest stage in flight
        if (kc + 2 < KCHUNKS) {
            asm volatile("s_waitcnt vmcnt(4) lgkmcnt(0)\ns_barrier" ::: "memory");
        } else {
            asm volatile("s_waitcnt vmcnt(0) lgkmcnt(0)\ns_barrier" ::: "memory");
        }
        MFMA16;
        unsigned short* t = p0; p0 = p1; p1 = p2; p2 = t;
    }

    // ---------------- epilogue: threshold + LDS-buffered escalate + symmetric reduce ----------------
    if (tid < TM) { cred_i[tid] = 0; cred_j[tid] = 0; }
    __syncthreads();

    const float thr_lo = 0.25f - DELTA;
    const float thr_hi = 0.25f + DELTA;
    const bool diag = (ib == jb);

    float sqj[4];
    int clsj[4], jv[4], jidx[4];
    #pragma unroll
    for (int jt = 0; jt < 4; jt++) {
        int j = jb + wj + jt * 16 + col;
        jidx[jt] = j;
        jv[jt] = (j < N_TOT);
        sqj[jt] = jv[jt] ? sqf[j] : 0.f;
        clsj[jt] = j / CLS_P;
    }

    int cj[4] = {0, 0, 0, 0};

    #pragma unroll
    for (int it = 0; it < 4; it++) {
        #pragma unroll
        for (int r = 0; r < 4; r++) {
            int irow = wi + it * 16 + quad * 4 + r;
            int i = ib + irow;
            bool iv = (i < N_TOT);
            float sqi = iv ? sqf[i] : 0.f;
            int clsi = i / CLS_P;
            int ci = 0;
            #pragma unroll
            for (int jt = 0; jt < 4; jt++) {
                int j = jidx[jt];
                bool ok = iv && jv[jt] && (clsj[jt] != clsi) && (!diag || j > i);
                float d2 = sqi + sqj[jt] - acc[it][jt][r] * INV_SCALE2;
                bool in = ok && (d2 < thr_lo);
                bool esc = ok && !in && (d2 < thr_hi);
                ci += in ? 1 : 0;
                cj[jt] += in ? 1 : 0;
                if (esc) {
                    int k = atomicAdd(&esc_n, 1);      // LDS atomic: fast
                    if (k < ESC_LOC) {
                        esc_buf[k] = make_int2(i, j);
                    } else {
                        int idx = atomicAdd(esc_cnt, 1);   // rare overflow path
                        if (idx < ESC_CAP) esc_list[idx] = make_int2(i, j);
                    }
                }
            }
            ci += __shfl_xor(ci, 1, 64);
            ci += __shfl_xor(ci, 2, 64);
            ci += __shfl_xor(ci, 4, 64);
            ci += __shfl_xor(ci, 8, 64);
            if (col == 0 && ci) atomicAdd(&cred_i[irow], ci);
        }
    }
    #pragma unroll
    for (int jt = 0; jt < 4; jt++) {
        int v = cj[jt];
        v += __shfl_xor(v, 16, 64);
        v += __shfl_xor(v, 32, 64);
        if (quad == 0 && v) atomicAdd(&cred_j[wj + jt * 16 + col], v);
    }
    __syncthreads();
    if (tid < TM) {
        int i = ib + tid;
        if (i < N_TOT && cred_i[tid]) atomicAdd(&counts[i], cred_i[tid]);
        int j = jb + tid;
        if (j < N_TOT && cred_j[tid]) atomicAdd(&counts[j], cred_j[tid]);
    }
    // flush escalation buffer: ONE global atomic per block
    if (tid == 0) {
        int n = esc_n; if (n > ESC_LOC) n = ESC_LOC;
        esc_n = n;
        esc_base = atomicAdd(esc_cnt, n);
    }
    __syncthreads();
    for (int k = tid; k < esc_n; k += 256) {
        int idx = esc_base + k;
        if (idx < ESC_CAP) esc_list[idx] = esc_buf[k];
    }
}

// ---------------- fp64 exact recheck: 16 lanes per pair, 4 pairs per wave ----------------
__global__ void escalate_kernel(const float* __restrict__ feats, const int* __restrict__ ids,
                                const double* __restrict__ sqd,
                                const int* __restrict__ esc_cnt, const int2* __restrict__ esc_list,
                                int* __restrict__ counts) {
    int n = *esc_cnt;
    if (n > ESC_CAP) n = ESC_CAP;
    int lane = threadIdx.x & 63;
    int sub = lane >> 4;         // pair slot within wave
    int l16 = lane & 15;
    int wglob = (blockIdx.x * blockDim.x + threadIdx.x) >> 6;
    int W = (gridDim.x * blockDim.x) >> 6;
    for (int p0 = wglob * 4; p0 < n; p0 += W * 4) {
        int p = p0 + sub;
        bool act = (p < n);
        int2 pr = act ? esc_list[p] : make_int2(0, 0);
        const float* xi = feats + (size_t)ids[pr.x] * D;
        const float* xj = feats + (size_t)ids[pr.y] * D;
        double s = 0.0;
        int k0 = l16 * 64;
        #pragma unroll
        for (int k = 0; k < 64; k += 4) {
            float4 a = *(const float4*)(xi + k0 + k);
            float4 b = *(const float4*)(xj + k0 + k);
            s += (double)a.x * b.x + (double)a.y * b.y + (double)a.z * b.z + (double)a.w * b.w;
        }
        s += __shfl_xor(s, 1, 64);
        s += __shfl_xor(s, 2, 64);
        s += __shfl_xor(s, 4, 64);
        s += __shfl_xor(s, 8, 64);
        if (act && l16 == 0) {
            double d2 = sqd[pr.x] + sqd[pr.y] - 2.0 * s;
            if (d2 < 0.25) {
                atomicAdd(&counts[pr.x], 1);
                atomicAdd(&counts[pr.y], 1);
            }
        }
    }
}

// ---------------- stable-argsort selection (one thread per p) ----------------
__global__ void sel_kernel(const int* __restrict__ counts, const int* __restrict__ ids,
                           int* __restrict__ out_ids, int pcb) {
    int c = blockIdx.x;
    __shared__ int lc[CLS_P];
    for (int p = threadIdx.x; p < CLS_P; p += blockDim.x)
        lc[p] = counts[c * CLS_P + p];
    __syncthreads();
    int p = threadIdx.x;
    if (p < CLS_P) {
        int cp = lc[p];
        int rank = 0;
        for (int qq = 0; qq < CLS_P; qq++) {
            int cq = lc[qq];
            rank += (cq < cp) || (cq == cp && qq < p);
        }
        if (rank < pcb)
            out_ids[c * pcb + rank] = ids[c * CLS_P + p];
    }
}

extern "C" void kernel_launch(void* const* d_in, const int* in_sizes, int n_in,
                              void* d_out, int out_size, void* d_ws, size_t ws_size,
                              hipStream_t stream) {
    const float* feats = (const float*)d_in[0];
    const int* ids = (const int*)d_in[1];
    int budget = out_size - N_TOT;
    int pcb = budget / NC;  // 200
    int* out = (int*)d_out;
    int* counts_out = out + NC * pcb;

    char* ws = (char*)d_ws;
    const size_t XH_OFF = 0;
    const size_t SQD_OFF = XH_OFF + (size_t)N_TOT * D * 2;           // 20.48 MB
    const size_t SQF_OFF = SQD_OFF + (size_t)N_TOT * 8;
    const size_t ESCC_OFF = (SQF_OFF + (size_t)N_TOT * 4 + 63) & ~(size_t)63;
    const size_t ESCL_OFF = ESCC_OFF + 64;

    unsigned short* Xh = (unsigned short*)(ws + XH_OFF);
    double* sqd = (double*)(ws + SQD_OFF);
    float* sqf = (float*)(ws + SQF_OFF);
    int* esc_cnt = (int*)(ws + ESCC_OFF);
    int2* esc_list = (int2*)(ws + ESCL_OFF);

    zero_kernel<<<(out_size + 255) / 256, 256, 0, stream>>>(out, out_size, esc_cnt);
    prep_kernel<<<N_TOT, 256, 0, stream>>>(feats, ids, Xh, sqd, sqf);
    dim3 grid(NTILE, NTILE);
    count_kernel<<<grid, 256, 0, stream>>>(Xh, sqf, counts_out, esc_cnt, esc_list);
    escalate_kernel<<<4096, 256, 0, stream>>>(feats, ids, sqd, esc_cnt, esc_list, counts_out);
    sel_kernel<<<NC, 1024, 0, stream>>>(counts_out, ids, out, pcb);
}

// Round 10
// 342.314 us; speedup vs baseline: 3.6208x; 1.0594x over previous
//
#include <hip/hip_runtime.h>

#define N_TOT 10000
#define CLS_P 1000
#define NC 10
#define D 1024

#define TM 128            // block tile (i and j)
#define DELTA 1.35e-5f
#define INV_SCALE2 4.8828125e-4f   // 2 / 4096  (Xh stores 64*x; acc = 4096*dot)
#define ESC_CAP (1 << 22)
#define ESC_LOC 256
#define KCHUNKS (D / 32)
#define NTILE ((N_TOT + TM - 1) / TM)   // 79

typedef _Float16 f16x8 __attribute__((ext_vector_type(8)));
typedef float f32x4 __attribute__((ext_vector_type(4)));
typedef const __attribute__((address_space(1))) unsigned int* gptr_t;
typedef __attribute__((address_space(3))) unsigned int* lptr_t;

// ---------------- zero output + escalation counter ----------------
__global__ void zero_kernel(int* __restrict__ out, int n, int* __restrict__ esc_cnt) {
    int i = blockIdx.x * blockDim.x + threadIdx.x;
    if (i < n) out[i] = 0;
    if (i == 0) *esc_cnt = 0;
}

// ---------------- gather + fp16(64x) + fp64 norms ----------------
__global__ void prep_kernel(const float* __restrict__ feats, const int* __restrict__ ids,
                            unsigned short* __restrict__ Xh,
                            double* __restrict__ sqd, float* __restrict__ sqf) {
    int row = blockIdx.x;
    int id = ids[row];
    const float4* rp = (const float4*)(feats + (size_t)id * D);
    float4 v = rp[threadIdx.x];  // 256 threads * 4 = 1024
    float f[4] = {v.x, v.y, v.z, v.w};
    ushort4 hv;
    unsigned short* hp = &hv.x;
    double s = 0.0;
    #pragma unroll
    for (int e = 0; e < 4; e++) {
        s += (double)f[e] * f[e];
        union { _Float16 h; unsigned short u; } cv;
        cv.h = (_Float16)(f[e] * 64.0f);   // RNE; x64 avoids fp16 denormals
        hp[e] = cv.u;
    }
    *(ushort4*)(Xh + (size_t)row * D + threadIdx.x * 4) = hv;

    #pragma unroll
    for (int off = 32; off > 0; off >>= 1)
        s += __shfl_down(s, off, 64);
    __shared__ double wsum[4];
    int lane = threadIdx.x & 63, wv = threadIdx.x >> 6;
    if (lane == 0) wsum[wv] = s;
    __syncthreads();
    if (threadIdx.x == 0) {
        double t = wsum[0] + wsum[1] + wsum[2] + wsum[3];
        sqd[row] = t;
        sqf[row] = (float)t;
    }
}

// ---------------- fp16 MFMA pairwise count (3-buf async, frag read-ahead) ----------------
__launch_bounds__(256, 3)
__global__ void count_kernel(const unsigned short* __restrict__ Xh,
                             const float* __restrict__ sqf,
                             int* __restrict__ counts,
                             int* __restrict__ esc_cnt, int2* __restrict__ esc_list) {
    // ---- band swizzle: 8 i-tiles per band, j fastest -> L2-local working set ----
    int bid = blockIdx.y * gridDim.x + blockIdx.x;
    int it_t = 0, jt_t = 0;
    {
        int rem = bid, band = 0;
        while (true) {
            int h = NTILE - band * 8; if (h > 8) h = 8;
            int area = h * NTILE;
            if (rem < area) { it_t = band * 8 + rem % h; jt_t = rem / h; break; }
            rem -= area; band++;
        }
    }
    const int ib = it_t * TM, jb = jt_t * TM;
    if (jb < ib) return;  // symmetric: only upper triangle of tiles

    // skip tiles that are entirely same-class
    {
        int ci0 = ib / CLS_P, ci1 = (ib + TM - 1) / CLS_P;
        int cj0 = jb / CLS_P, cj1 = (jb + TM - 1) / CLS_P;
        if (ci0 == ci1 && cj0 == cj1 && ci0 == cj0) return;
    }

    // 3 buffers x (A 8KB + B 8KB) = 48 KB
    __shared__ unsigned short S[3 * 8192];
    __shared__ int cred_i[TM], cred_j[TM];
    __shared__ int esc_n, esc_base;
    __shared__ int2 esc_buf[ESC_LOC];

    const int tid = threadIdx.x;
    const int lane = tid & 63, w = tid >> 6;
    const int wi = (w & 1) * 64, wj = (w >> 1) * 64;
    const int quad = lane >> 4, col = lane & 15;

    if (tid == 0) esc_n = 0;

    // staging: waves 0,1 -> A (rows of ib); waves 2,3 -> B (rows of jb)
    const int warr = w >> 1;
    const int w01 = w & 1;
    const int rl0 = lane >> 2;      // 0..15 row within 16-row call group
    const int slot = lane & 3;      // dest k-slot
    const int q = (slot - rl0 - (rl0 >> 2)) & 3;   // source k-quarter (swizzle)
    const int rowbase = warr ? jb : ib;

    const unsigned short* src[4];
    #pragma unroll
    for (int b = 0; b < 4; b++) {
        int grow = rowbase + b * 32 + w01 * 16 + rl0;
        if (grow > N_TOT - 1) grow = N_TOT - 1;
        src[b] = Xh + (size_t)grow * D + q * 8;
    }

#define STAGE(KC_, BUFBASE_)                                                     \
    {                                                                            \
        _Pragma("unroll")                                                        \
        for (int b = 0; b < 4; b++) {                                            \
            __builtin_amdgcn_global_load_lds(                                    \
                (gptr_t)(src[b] + (KC_) * 32),                                   \
                (lptr_t)((BUFBASE_) + warr * 4096 + b * 1024 + w01 * 512),       \
                16, 0, 0);                                                       \
        }                                                                        \
    }

#define FRAGS_(AH, BH, BUFBASE_)                                                 \
    {                                                                            \
        _Pragma("unroll")                                                        \
        for (int t = 0; t < 4; t++) {                                            \
            int rA = wi + t * 16 + col;                                          \
            int sA = (quad + rA + (rA >> 2)) & 3;                                \
            AH[t] = *(const f16x8*)((BUFBASE_) + rA * 32 + sA * 8);              \
            int rB = wj + t * 16 + col;                                          \
            int sB = (quad + rB + (rB >> 2)) & 3;                                \
            BH[t] = *(const f16x8*)((BUFBASE_) + 4096 + rB * 32 + sB * 8);       \
        }                                                                        \
    }

#define MFMA16_(AH, BH)                                                          \
    {                                                                            \
        _Pragma("unroll")                                                        \
        for (int it = 0; it < 4; it++)                                           \
            _Pragma("unroll")                                                    \
            for (int jt = 0; jt < 4; jt++)                                       \
                acc[it][jt] = __builtin_amdgcn_mfma_f32_16x16x32_f16(AH[it], BH[jt], acc[it][jt], 0, 0, 0); \
    }

#define WAIT4_BAR asm volatile("s_waitcnt vmcnt(4)\ns_barrier" ::: "memory")
#define WAIT0_BAR asm volatile("s_waitcnt vmcnt(0)\ns_barrier" ::: "memory")

    f32x4 acc[4][4];
    #pragma unroll
    for (int it = 0; it < 4; it++)
        #pragma unroll
        for (int jt = 0; jt < 4; jt++)
            acc[it][jt] = (f32x4){0.f, 0.f, 0.f, 0.f};

    f16x8 ah0[4], bh0[4], ah1[4], bh1[4];   // two named frag sets (phase parity)

    unsigned short* p0 = S;                 // data kc   (cur, already in regs)
    unsigned short* p1 = S + 8192;          // data kc+1 (frags read this phase)
    unsigned short* p2 = S + 16384;         // free -> staging kc+2

    // prologue: stage kc0,kc1; retire kc0 (keep kc1 in flight); preload frags0
    STAGE(0, p0);
    STAGE(1, p1);
    WAIT4_BAR;
    FRAGS_(ah0, bh0, p0);

    for (int kc = 0; kc < KCHUNKS - 2; kc += 2) {
        // ---- phase m=kc (cur set0): stage kc+2, read-ahead frags kc+1 -> set1 ----
        STAGE(kc + 2, p2);
        WAIT4_BAR;                 // retire stage(kc+1) everywhere; gate p2 overwrite
        FRAGS_(ah1, bh1, p1);      // ds_reads overlap MFMA below
        MFMA16_(ah0, bh0);
        { unsigned short* t = p0; p0 = p1; p1 = p2; p2 = t; }

        // ---- phase m=kc+1 (cur set1): stage kc+3, read-ahead frags kc+2 -> set0 ----
        STAGE(kc + 3, p2);
        WAIT4_BAR;
        FRAGS_(ah0, bh0, p1);
        MFMA16_(ah1, bh1);
        { unsigned short* t = p0; p0 = p1; p1 = p2; p2 = t; }
    }
    // tail: phase 30 (cur set0), phase 31 (cur set1)
    WAIT0_BAR;                     // retire stage(31)
    FRAGS_(ah1, bh1, p1);
    MFMA16_(ah0, bh0);
    MFMA16_(ah1, bh1);

    // ---------------- epilogue: threshold + LDS-buffered escalate + symmetric reduce ----------------
    if (tid < TM) { cred_i[tid] = 0; cred_j[tid] = 0; }
    __syncthreads();

    const float thr_lo = 0.25f - DELTA;
    const float thr_hi = 0.25f + DELTA;
    const bool diag = (ib == jb);

    float sqj[4];
    int clsj[4], jv[4], jidx[4];
    #pragma unroll
    for (int jt = 0; jt < 4; jt++) {
        int j = jb + wj + jt * 16 + col;
        jidx[jt] = j;
        jv[jt] = (j < N_TOT);
        sqj[jt] = jv[jt] ? sqf[j] : 0.f;
        clsj[jt] = j / CLS_P;
    }

    int cj[4] = {0, 0, 0, 0};

    #pragma unroll
    for (int it = 0; it < 4; it++) {
        #pragma unroll
        for (int r = 0; r < 4; r++) {
            int irow = wi + it * 16 + quad * 4 + r;
            int i = ib + irow;
            bool iv = (i < N_TOT);
            float sqi = iv ? sqf[i] : 0.f;
            int clsi = i / CLS_P;
            int ci = 0;
            #pragma unroll
            for (int jt = 0; jt < 4; jt++) {
                int j = jidx[jt];
                bool ok = iv && jv[jt] && (clsj[jt] != clsi) && (!diag || j > i);
                float d2 = sqi + sqj[jt] - acc[it][jt][r] * INV_SCALE2;
                bool in = ok && (d2 < thr_lo);
                bool esc = ok && !in && (d2 < thr_hi);
                ci += in ? 1 : 0;
                cj[jt] += in ? 1 : 0;
                if (esc) {
                    int k = atomicAdd(&esc_n, 1);      // LDS atomic: fast
                    if (k < ESC_LOC) {
                        esc_buf[k] = make_int2(i, j);
                    } else {
                        int idx = atomicAdd(esc_cnt, 1);   // rare overflow path
                        if (idx < ESC_CAP) esc_list[idx] = make_int2(i, j);
                    }
                }
            }
            ci += __shfl_xor(ci, 1, 64);
            ci += __shfl_xor(ci, 2, 64);
            ci += __shfl_xor(ci, 4, 64);
            ci += __shfl_xor(ci, 8, 64);
            if (col == 0 && ci) atomicAdd(&cred_i[irow], ci);
        }
    }
    #pragma unroll
    for (int jt = 0; jt < 4; jt++) {
        int v = cj[jt];
        v += __shfl_xor(v, 16, 64);
        v += __shfl_xor(v, 32, 64);
        if (quad == 0 && v) atomicAdd(&cred_j[wj + jt * 16 + col], v);
    }
    __syncthreads();
    if (tid < TM) {
        int i = ib + tid;
        if (i < N_TOT && cred_i[tid]) atomicAdd(&counts[i], cred_i[tid]);
        int j = jb + tid;
        if (j < N_TOT && cred_j[tid]) atomicAdd(&counts[j], cred_j[tid]);
    }
    // flush escalation buffer: ONE global atomic per block
    if (tid == 0) {
        int n = esc_n; if (n > ESC_LOC) n = ESC_LOC;
        esc_n = n;
        esc_base = atomicAdd(esc_cnt, n);
    }
    __syncthreads();
    for (int k = tid; k < esc_n; k += 256) {
        int idx = esc_base + k;
        if (idx < ESC_CAP) esc_list[idx] = esc_buf[k];
    }
}

// ---------------- fp64 exact recheck: 16 lanes per pair, 4 pairs per wave ----------------
__global__ void escalate_kernel(const float* __restrict__ feats, const int* __restrict__ ids,
                                const double* __restrict__ sqd,
                                const int* __restrict__ esc_cnt, const int2* __restrict__ esc_list,
                                int* __restrict__ counts) {
    int n = *esc_cnt;
    if (n > ESC_CAP) n = ESC_CAP;
    int lane = threadIdx.x & 63;
    int sub = lane >> 4;         // pair slot within wave
    int l16 = lane & 15;
    int wglob = (blockIdx.x * blockDim.x + threadIdx.x) >> 6;
    int W = (gridDim.x * blockDim.x) >> 6;
    for (int p0 = wglob * 4; p0 < n; p0 += W * 4) {
        int p = p0 + sub;
        bool act = (p < n);
        int2 pr = act ? esc_list[p] : make_int2(0, 0);
        const float* xi = feats + (size_t)ids[pr.x] * D;
        const float* xj = feats + (size_t)ids[pr.y] * D;
        double s = 0.0;
        int k0 = l16 * 64;
        #pragma unroll
        for (int k = 0; k < 64; k += 4) {
            float4 a = *(const float4*)(xi + k0 + k);
            float4 b = *(const float4*)(xj + k0 + k);
            s += (double)a.x * b.x + (double)a.y * b.y + (double)a.z * b.z + (double)a.w * b.w;
        }
        s += __shfl_xor(s, 1, 64);
        s += __shfl_xor(s, 2, 64);
        s += __shfl_xor(s, 4, 64);
        s += __shfl_xor(s, 8, 64);
        if (act && l16 == 0) {
            double d2 = sqd[pr.x] + sqd[pr.y] - 2.0 * s;
            if (d2 < 0.25) {
                atomicAdd(&counts[pr.x], 1);
                atomicAdd(&counts[pr.y], 1);
            }
        }
    }
}

// ---------------- stable-argsort selection (one thread per p) ----------------
__global__ void sel_kernel(const int* __restrict__ counts, const int* __restrict__ ids,
                           int* __restrict__ out_ids, int pcb) {
    int c = blockIdx.x;
    __shared__ int lc[CLS_P];
    for (int p = threadIdx.x; p < CLS_P; p += blockDim.x)
        lc[p] = counts[c * CLS_P + p];
    __syncthreads();
    int p = threadIdx.x;
    if (p < CLS_P) {
        int cp = lc[p];
        int rank = 0;
        for (int qq = 0; qq < CLS_P; qq++) {
            int cq = lc[qq];
            rank += (cq < cp) || (cq == cp && qq < p);
        }
        if (rank < pcb)
            out_ids[c * pcb + rank] = ids[c * CLS_P + p];
    }
}

extern "C" void kernel_launch(void* const* d_in, const int* in_sizes, int n_in,
                              void* d_out, int out_size, void* d_ws, size_t ws_size,
                              hipStream_t stream) {
    const float* feats = (const float*)d_in[0];
    const int* ids = (const int*)d_in[1];
    int budget = out_size - N_TOT;
    int pcb = budget / NC;  // 200
    int* out = (int*)d_out;
    int* counts_out = out + NC * pcb;

    char* ws = (char*)d_ws;
    const size_t XH_OFF = 0;
    const size_t SQD_OFF = XH_OFF + (size_t)N_TOT * D * 2;           // 20.48 MB
    const size_t SQF_OFF = SQD_OFF + (size_t)N_TOT * 8;
    const size_t ESCC_OFF = (SQF_OFF + (size_t)N_TOT * 4 + 63) & ~(size_t)63;
    const size_t ESCL_OFF = ESCC_OFF + 64;

    unsigned short* Xh = (unsigned short*)(ws + XH_OFF);
    double* sqd = (double*)(ws + SQD_OFF);
    float* sqf = (float*)(ws + SQF_OFF);
    int* esc_cnt = (int*)(ws + ESCC_OFF);
    int2* esc_list = (int2*)(ws + ESCL_OFF);

    zero_kernel<<<(out_size + 255) / 256, 256, 0, stream>>>(out, out_size, esc_cnt);
    prep_kernel<<<N_TOT, 256, 0, stream>>>(feats, ids, Xh, sqd, sqf);
    dim3 grid(NTILE, NTILE);
    count_kernel<<<grid, 256, 0, stream>>>(Xh, sqf, counts_out, esc_cnt, esc_list);
    escalate_kernel<<<4096, 256, 0, stream>>>(feats, ids, sqd, esc_cnt, esc_list, counts_out);
    sel_kernel<<<NC, 1024, 0, stream>>>(counts_out, ids, out, pcb);
}